// Round 14
// baseline (253.028 us; speedup 1.0000x reference)
//
#include <hip/hip_runtime.h>
#include <cstddef>

#define L_SEQ 784
#define DIM 384
#define B_SZ 16
#define NH 8
#define QKD 32
#define VD 128
#define EDIM 1536   // NH*(2*QKD+VD)
#define RESN 25
#define NPTS 625    // RESN*RESN
#define ODIM 1024   // NH*VD
#define NKT 13      // ceil(784/64) k-tiles
#define QKVD 192    // 2*QKD + VD
#define QBLK 128    // q-rows per block (8 waves x 16)
#define NQT8 7      // ceil(784/128) q-tiles

typedef short s16x8 __attribute__((ext_vector_type(8)));
typedef short s16x4 __attribute__((ext_vector_type(4)));
typedef float f32x4v __attribute__((ext_vector_type(4)));

__device__ __forceinline__ short f2bf(float f) {
    union { float f; unsigned u; } c; c.f = f;
    unsigned u = c.u;
    return (short)((u + 0x7FFFu + ((u >> 16) & 1u)) >> 16);
}

__device__ __forceinline__ s16x8 ld_frag(const short* p) {
    s16x4 lo = *(const s16x4*)p;
    s16x4 hi = *(const s16x4*)(p + 4);
    s16x8 r;
    r[0] = lo[0]; r[1] = lo[1]; r[2] = lo[2]; r[3] = lo[3];
    r[4] = hi[0]; r[5] = hi[1]; r[6] = hi[2]; r[7] = hi[3];
    return r;
}

__device__ __forceinline__ void st_frag(short* p, s16x8 w) {
    s16x4 lo, hi;
    lo[0] = w[0]; lo[1] = w[1]; lo[2] = w[2]; lo[3] = w[3];
    hi[0] = w[4]; hi[1] = w[5]; hi[2] = w[6]; hi[3] = w[7];
    *(s16x4*)p = lo;
    *(s16x4*)(p + 4) = hi;
}

// Raw workgroup barrier that does NOT drain vmcnt (global prefetches stay in
// flight); waits only this wave's LDS ops, then s_barrier.
__device__ __forceinline__ void wg_barrier_lds() {
    asm volatile("s_waitcnt lgkmcnt(0)" ::: "memory");
    __builtin_amdgcn_s_barrier();
    asm volatile("" ::: "memory");
}

// ---------------------------------------------------------------------------
// fp32 -> bf16 bulk convert, all three tensors in ONE launch (8 elts/thread)
// ---------------------------------------------------------------------------
__global__ __launch_bounds__(256) void cvt_bf16_all(const float* __restrict__ s0, short* __restrict__ d0, int n0,
                                                    const float* __restrict__ s1, short* __restrict__ d1, int n1,
                                                    const float* __restrict__ s2, short* __restrict__ d2, int n2) {
    int i = blockIdx.x * 256 + threadIdx.x;
    const float* s;
    short* d;
    int li;
    if (i < n0) { s = s0; d = d0; li = i; }
    else if (i < n0 + n1) { s = s1; d = d1; li = i - n0; }
    else if (i < n0 + n1 + n2) { s = s2; d = d2; li = i - n0 - n1; }
    else return;
    const float4* sp = (const float4*)(s + (size_t)li * 8);
    float4 a = sp[0], c = sp[1];
    s16x8 w;
    w[0] = f2bf(a.x); w[1] = f2bf(a.y); w[2] = f2bf(a.z); w[3] = f2bf(a.w);
    w[4] = f2bf(c.x); w[5] = f2bf(c.y); w[6] = f2bf(c.z); w[7] = f2bf(c.w);
    *(s16x8*)(d + (size_t)li * 8) = w;
}

// ---------------------------------------------------------------------------
// cubic interpolation weight (a = -0.75) + inline tap computation
// ---------------------------------------------------------------------------
__device__ __forceinline__ float cubic_w(float x) {
    float ax = fabsf(x);
    const float a = -0.75f;
    float w1 = ((a + 2.0f) * ax - (a + 3.0f)) * ax * ax + 1.0f;
    float w2 = a * (((ax - 5.0f) * ax + 8.0f) * ax - 4.0f);
    return ax <= 1.0f ? w1 : (ax < 2.0f ? w2 : 0.0f);
}

__device__ __forceinline__ void interp_taps(int o, float* w, int* ty, int* tx) {
    const float scale = 625.0f / 784.0f;
    float src = ((float)o + 0.5f) * scale - 0.5f;
    float f = floorf(src);
    float t = src - f;
    int fi = (int)f;
    w[0] = cubic_w(t + 1.0f);
    w[1] = cubic_w(t);
    w[2] = cubic_w(1.0f - t);
    w[3] = cubic_w(2.0f - t);
#pragma unroll
    for (int j = 0; j < 4; ++j) {
        int idx = fi - 1 + j;
        idx = idx < 0 ? 0 : (idx > NPTS - 1 ? NPTS - 1 : idx);
        ty[j] = idx / RESN;
        tx[j] = idx % RESN;
    }
}

// ---------------------------------------------------------------------------
// biasT[h][p][o]: per-head table in LDS; 4 o-outputs/thread, float4 store.
// Interp taps computed inline (r13-verified).
// ---------------------------------------------------------------------------
__global__ __launch_bounds__(256) void bias_kernel(const float* __restrict__ table,
                                                   float* __restrict__ biasT) {
    __shared__ float Tl[NPTS];
    const int h = blockIdx.y;
    {
        const float* th = table + (size_t)h * NPTS;
        for (int i = threadIdx.x; i < NPTS; i += 256) Tl[i] = th[i];
    }
    __syncthreads();

    int base = (blockIdx.x * 256 + threadIdx.x) * 4;
    if (base >= L_SEQ * L_SEQ) return;
    int p = base / L_SEQ;
    int o0 = base - p * L_SEQ;

    float wp[4]; int py[4], px[4];
    interp_taps(p, wp, py, px);

    float4 res;
    float* rp = (float*)&res;
#pragma unroll
    for (int u = 0; u < 4; ++u) {
        int o = o0 + u;
        float wo[4]; int oy[4], ox[4];
        interp_taps(o, wo, oy, ox);
        float s = 0.0f;
#pragma unroll
        for (int a = 0; a < 4; ++a) {
#pragma unroll
            for (int b = 0; b < 4; ++b) {
                int dy = abs(oy[a] - py[b]);
                int dx = abs(ox[a] - px[b]);
                s += wo[a] * wp[b] * Tl[dy * RESN + dx];
            }
        }
        rp[u] = s;
    }
    *(float4*)(biasT + (size_t)h * L_SEQ * L_SEQ + base) = res;
}

// ---------------------------------------------------------------------------
// qkv GEMM (r10-verified pipeline): 128x128 tile, dbuf LDS, ONE non-draining
// barrier per K-step, global loads 2 tiles ahead.  NEW (r14): XCD-aware
// chunked block swizzle (T1) — 1176 blocks, 1176%8==0, swz=(bid%8)*147+bid/8;
// consecutive swz within an XCD share one B-panel -> XCD-L2 resident.
// Outputs:
//   qkb[bh][seq][64] : q feats 0..31 (pre-scaled), k feats 32..63
//   vT [bh][vd][seq] : V transposed (PV staging layout)
// ---------------------------------------------------------------------------
#define QKV_KIT 12   // DIM/32
#define QKV_NWG 1176 // 98*12
__global__ __launch_bounds__(256) void qkv_gemm_mfma(const short* __restrict__ Xb,
                                                     const short* __restrict__ Wb,
                                                     short* __restrict__ qkb,
                                                     short* __restrict__ vT) {
    __shared__ short Ak[2][128][48];
    __shared__ short Bk[2][128][48];

    const int tid = threadIdx.x;
    const int wv = tid >> 6;
    const int lane = tid & 63;
    const int quad = lane >> 4;
    const int l15 = lane & 15;
    const int wr = wv >> 1, wc = wv & 1;

    // T1 XCD swizzle (bijective: 8 groups x 147 = 1176)
    const int bid = blockIdx.x;
    const int swz = (bid & 7) * (QKV_NWG / 8) + (bid >> 3);
    const int mt = swz % 98;
    const int nt = swz / 98;
    const int m0 = mt * 128;
    const int n0 = nt * 128;

    const int srow = tid >> 2;
    const int sseg = (tid & 3) * 8;
    const short* xr0 = Xb + (size_t)(m0 + srow) * DIM + sseg;
    const short* xr1 = Xb + (size_t)(m0 + srow + 64) * DIM + sseg;
    const short* wr0 = Wb + (size_t)(n0 + srow) * DIM + sseg;
    const short* wr1 = Wb + (size_t)(n0 + srow + 64) * DIM + sseg;

    f32x4v acc[4][4];
#pragma unroll
    for (int i = 0; i < 4; ++i)
#pragma unroll
        for (int j = 0; j < 4; ++j) { acc[i][j][0] = 0.f; acc[i][j][1] = 0.f; acc[i][j][2] = 0.f; acc[i][j][3] = 0.f; }

    // ---- prologue: tile 0 -> LDS[0]; issue tile-1 loads ----
    s16x8 ra0 = *(const s16x8*)(xr0);
    s16x8 ra1 = *(const s16x8*)(xr1);
    s16x8 rb0 = *(const s16x8*)(wr0);
    s16x8 rb1 = *(const s16x8*)(wr1);
    *(s16x8*)&Ak[0][srow][sseg] = ra0;
    *(s16x8*)&Ak[0][srow + 64][sseg] = ra1;
    *(s16x8*)&Bk[0][srow][sseg] = rb0;
    *(s16x8*)&Bk[0][srow + 64][sseg] = rb1;
    ra0 = *(const s16x8*)(xr0 + 32);
    ra1 = *(const s16x8*)(xr1 + 32);
    rb0 = *(const s16x8*)(wr0 + 32);
    rb1 = *(const s16x8*)(wr1 + 32);
    wg_barrier_lds();

    int buf = 0;
    for (int kt = 0; kt < QKV_KIT; ++kt) {
        s16x8 af[4], bfr[4];
#pragma unroll
        for (int i = 0; i < 4; ++i) af[i] = *(const s16x8*)&Ak[buf][wr * 64 + i * 16 + l15][quad * 8];
#pragma unroll
        for (int j = 0; j < 4; ++j) bfr[j] = *(const s16x8*)&Bk[buf][wc * 64 + j * 16 + l15][quad * 8];

        if (kt + 1 < QKV_KIT) {
            *(s16x8*)&Ak[buf ^ 1][srow][sseg] = ra0;
            *(s16x8*)&Ak[buf ^ 1][srow + 64][sseg] = ra1;
            *(s16x8*)&Bk[buf ^ 1][srow][sseg] = rb0;
            *(s16x8*)&Bk[buf ^ 1][srow + 64][sseg] = rb1;
            if (kt + 2 < QKV_KIT) {
                int k0n = (kt + 2) * 32;
                ra0 = *(const s16x8*)(xr0 + k0n);
                ra1 = *(const s16x8*)(xr1 + k0n);
                rb0 = *(const s16x8*)(wr0 + k0n);
                rb1 = *(const s16x8*)(wr1 + k0n);
            }
        }

        __builtin_amdgcn_s_setprio(1);
#pragma unroll
        for (int i = 0; i < 4; ++i)
#pragma unroll
            for (int j = 0; j < 4; ++j)
                acc[i][j] = __builtin_amdgcn_mfma_f32_16x16x32_bf16(af[i], bfr[j], acc[i][j], 0, 0, 0);
        __builtin_amdgcn_s_setprio(0);

        if (kt + 1 < QKV_KIT) {
            wg_barrier_lds();
            buf ^= 1;
        }
    }

    const float SCALE = 0.17677669529663687f;  // 32^-0.5, folded into q rows

#pragma unroll
    for (int j = 0; j < 4; ++j) {
        int n = n0 + wc * 64 + j * 16 + l15;
        int head = n / QKVD;
        int rr = n - head * QKVD;
        if (rr < 64) {
            float sc = rr < QKD ? SCALE : 1.0f;
#pragma unroll
            for (int i = 0; i < 4; ++i) {
                int mbase = m0 + wr * 64 + i * 16 + quad * 4;
                int bidx = mbase / L_SEQ;       // 4-run never crosses (784 % 4 == 0)
                int l0 = mbase - bidx * L_SEQ;
                size_t base = ((size_t)(bidx * NH + head) * L_SEQ + l0) * 64 + rr;
#pragma unroll
                for (int r = 0; r < 4; ++r)
                    qkb[base + (size_t)r * 64] = f2bf(acc[i][j][r] * sc);
            }
        } else {
            int vd = rr - 64;
#pragma unroll
            for (int i = 0; i < 4; ++i) {
                int mbase = m0 + wr * 64 + i * 16 + quad * 4;
                int bidx = mbase / L_SEQ;
                int l0 = mbase - bidx * L_SEQ;
                s16x4 pk;
#pragma unroll
                for (int r = 0; r < 4; ++r) pk[r] = f2bf(acc[i][j][r]);
                *(s16x4*)&vT[((size_t)(bidx * NH + head) * VD + vd) * L_SEQ + l0] = pk;
            }
        }
    }
}

// ---------------------------------------------------------------------------
// Flash attention v13 (r9-verified, ~99 us): UNCHANGED.
// ---------------------------------------------------------------------------
__global__ __launch_bounds__(512, 4) void flash_attn_mfma13(const short* __restrict__ qkb,
                                                            const short* __restrict__ vT,
                                                            const float* __restrict__ biasT,
                                                            short* __restrict__ o2) {
    __shared__ short Vt[2][VD][68];   // [buf][v-col][k 0..63]  34816 B
    __shared__ short Ps[QBLK][72];    // [q-row][k 0..63] wave-private  18432 B

    const int tid = threadIdx.x;
    const int wv = tid >> 6;          // 0..7
    const int lane = tid & 63;
    const int quad = lane >> 4;
    const int l15 = lane & 15;

    const int h = blockIdx.x & 7;
    const int slot = blockIdx.x >> 3;
    const int b = slot / NQT8;
    const int qt = slot - b * NQT8;
    const int bh = b * NH + h;
    const int q0 = qt * QBLK;

    const short* qkp = qkb + (size_t)bh * L_SEQ * 64;
    const short* vp = vT + (size_t)bh * VD * L_SEQ;

    // V staging addressing: 512 threads cover 128 vd-rows x 4 col-groups of 16
    const int vd = tid >> 2;           // v-dim 0..127
    const int vc0 = (tid & 3) * 16;    // k-col 0/16/32/48
    const short* vline = vp + (size_t)vd * L_SEQ;

    // ---- Q fragment (B operand): lane l15 = q-row, quad*8 = d ----
    int gqq = q0 + wv * 16 + l15;
    if (gqq > L_SEQ - 1) gqq = L_SEQ - 1;   // dup tail row; discarded at store
    const float* brow = biasT + (size_t)h * L_SEQ * L_SEQ + (size_t)gqq * L_SEQ;
    s16x8 qfrag = *(const s16x8*)(qkp + (size_t)gqq * 64 + quad * 8);

    // ---- prologue: V tile 0 -> Vt[0]; issue tile-1 loads ----
    s16x8 va[2];
#pragma unroll
    for (int j = 0; j < 2; ++j) va[j] = *(const s16x8*)(vline + vc0 + j * 8);
#pragma unroll
    for (int j = 0; j < 2; ++j) st_frag(&Vt[0][vd][vc0 + j * 8], va[j]);
    {
#pragma unroll
        for (int j = 0; j < 2; ++j) {
            int cb = 64 + vc0 + j * 8;
            va[j] = *(const s16x8*)(vline + cb);
        }
    }

    // ---- K fragments (A operand) + bias row-slices for tile 0 ----
    s16x8 kf[4];
    f32x4v bcur[4];
#pragma unroll
    for (int t = 0; t < 4; ++t) {
        kf[t] = *(const s16x8*)(qkp + (size_t)(t * 16 + l15) * 64 + 32 + quad * 8);
        float4 bv = *(const float4*)(brow + t * 16 + quad * 4);
        bcur[t][0] = bv.x; bcur[t][1] = bv.y; bcur[t][2] = bv.z; bcur[t][3] = bv.w;
    }

    wg_barrier_lds();   // Vt[0] visible; global prefetches stay in flight

    f32x4v oacc[8];
#pragma unroll
    for (int vt = 0; vt < 8; ++vt) { oacc[vt][0] = 0.f; oacc[vt][1] = 0.f; oacc[vt][2] = 0.f; oacc[vt][3] = 0.f; }
    float lp = 0.f;     // this lane's q-row partial denominator
    int buf = 0;

    for (int kt = 0; kt < NKT; ++kt) {
        const int k0 = kt * 64;

        // ---- QK^T swapped: D[m=k][n=q]; lane holds q=l15, k=t*16+quad*4+r ----
        f32x4v s[4];
        __builtin_amdgcn_s_setprio(1);
#pragma unroll
        for (int t = 0; t < 4; ++t) {
            f32x4v z; z[0] = 0.f; z[1] = 0.f; z[2] = 0.f; z[3] = 0.f;
            s[t] = __builtin_amdgcn_mfma_f32_16x16x32_bf16(kf[t], qfrag, z, 0, 0, 0);
        }
        __builtin_amdgcn_s_setprio(0);
#pragma unroll
        for (int t = 0; t < 4; ++t) s[t] += bcur[t];

        // ---- prefetch K + bias for tile kt+1 (hidden under exp/P/PV) ----
        if (kt + 1 < NKT) {
            int k0n = k0 + 64;
#pragma unroll
            for (int t = 0; t < 4; ++t) {
                int row = k0n + t * 16 + l15;
                if (row > L_SEQ - 1) row = L_SEQ - 1;
                kf[t] = *(const s16x8*)(qkp + (size_t)row * 64 + 32 + quad * 8);
                int c = k0n + t * 16 + quad * 4;
                if (c > L_SEQ - 4) c = L_SEQ - 4;
                float4 bv = *(const float4*)(brow + c);
                bcur[t][0] = bv.x; bcur[t][1] = bv.y; bcur[t][2] = bv.z; bcur[t][3] = bv.w;
            }
        }

        // ---- k-tail mask (uniform per (t,quad): 784 % 4 == 0) ----
        if (kt == NKT - 1) {
#pragma unroll
            for (int t = 0; t < 4; ++t) {
                if (k0 + t * 16 + quad * 4 >= L_SEQ) {
                    s[t][0] = -1e30f; s[t][1] = -1e30f; s[t][2] = -1e30f; s[t][3] = -1e30f;
                }
            }
        }

        // ---- exp + pack + packed P store (4x ds_write_b64, wave-private) ----
#pragma unroll
        for (int t = 0; t < 4; ++t) {
            s16x4 pk;
#pragma unroll
            for (int r = 0; r < 4; ++r) {
                float p = __expf(s[t][r]);
                lp += p;
                pk[r] = f2bf(p);
            }
            *(s16x4*)&Ps[wv * 16 + l15][t * 16 + quad * 4] = pk;
        }

        // ---- stage V tile kt+1 into IDLE buffer (no WAR barrier needed) ----
        if (kt + 1 < NKT) {
#pragma unroll
            for (int j = 0; j < 2; ++j) st_frag(&Vt[buf ^ 1][vd][vc0 + j * 8], va[j]);
            if (kt + 2 < NKT) {
                int k0n2 = (kt + 2) * 64;
#pragma unroll
                for (int j = 0; j < 2; ++j) {
                    int cb = k0n2 + vc0 + j * 8;
                    if (cb > L_SEQ - 8) cb = L_SEQ - 8;
                    va[j] = *(const s16x8*)(vline + cb);
                }
            }
        }

        // ---- P fragments (same-wave LDS ordering; no barrier) ----
        s16x8 pf0 = *(const s16x8*)&Ps[wv * 16 + l15][quad * 8];
        s16x8 pf1 = *(const s16x8*)&Ps[wv * 16 + l15][32 + quad * 8];

        // ---- PV: 16 MFMAs reading Vt[buf] ----
        __builtin_amdgcn_s_setprio(1);
#pragma unroll
        for (int vt = 0; vt < 8; ++vt) {
            int n = vt * 16 + l15;
            s16x8 b0 = ld_frag(&Vt[buf][n][quad * 8]);
            oacc[vt] = __builtin_amdgcn_mfma_f32_16x16x32_bf16(pf0, b0, oacc[vt], 0, 0, 0);
            s16x8 b1 = ld_frag(&Vt[buf][n][32 + quad * 8]);
            oacc[vt] = __builtin_amdgcn_mfma_f32_16x16x32_bf16(pf1, b1, oacc[vt], 0, 0, 0);
        }
        __builtin_amdgcn_s_setprio(0);

        // ---- single barrier per tile: V(kt+1) writes visible to all waves ----
        if (kt + 1 < NKT) {
            wg_barrier_lds();
            buf ^= 1;
        }
    }

    // ---- epilogue (r3/r6-verified): row sum across the 4 quads, store ----
    float lsum = lp;
    lsum += __shfl_xor(lsum, 16);
    lsum += __shfl_xor(lsum, 32);
    float inv[4];
#pragma unroll
    for (int r = 0; r < 4; ++r)
        inv[r] = 1.0f / __shfl(lsum, quad * 4 + r, 16);

#pragma unroll
    for (int r = 0; r < 4; ++r) {
        int gqs = q0 + wv * 16 + quad * 4 + r;
        if (gqs >= L_SEQ) continue;
        short* dst = o2 + ((size_t)b * L_SEQ + gqs) * ODIM + h * VD;
#pragma unroll
        for (int vt = 0; vt < 8; ++vt)
            dst[vt * 16 + l15] = f2bf(oacc[vt][r] * inv[r]);
    }
}

// ---------------------------------------------------------------------------
// proj GEMM (r13 geometry: 64x128, 4 waves 1x4, acc[4][2], dbuf pipeline).
// NEW (r14): bijective XCD swizzle (m204 variant; 588 = 8*73 + 4, so the
// simple modulo swizzle would be non-bijective — ERRATA #11).
// out = o2 @ WprojT + bproj (fp32)
// ---------------------------------------------------------------------------
#define PROJ_KIT 32   // ODIM/32
__global__ __launch_bounds__(256) void proj_gemm_mfma(const short* __restrict__ Xb,
                                                      const short* __restrict__ Wb,
                                                      const float* __restrict__ bproj,
                                                      float* __restrict__ out) {
    __shared__ short Ak[2][64][48];
    __shared__ short Bk[2][128][48];

    const int tid = threadIdx.x;
    const int wv = tid >> 6;          // 0..3 (n-quadrant)
    const int lane = tid & 63;
    const int quad = lane >> 4;
    const int l15 = lane & 15;

    // bijective XCD swizzle: nwg=588, q=73, r=4, q+1=74, r*(q+1)=296
    const int bid = blockIdx.x;
    const int xcd = bid & 7;
    const int chunk = bid >> 3;
    const int swz = (xcd < 4 ? xcd * 74 : 296 + (xcd - 4) * 73) + chunk;
    const int mt = swz % 196;
    const int nt = swz / 196;
    const int m0 = mt * 64;
    const int n0 = nt * 128;

    // staging: A 64x32 (1 frag/thread), B 128x32 (2 frags/thread)
    const int srow = tid >> 2;          // 0..63
    const int sseg = (tid & 3) * 8;     // 0/8/16/24
    const short* ga  = Xb + (size_t)(m0 + srow) * ODIM + sseg;
    const short* gb0 = Wb + (size_t)(n0 + srow) * ODIM + sseg;
    const short* gb1 = Wb + (size_t)(n0 + srow + 64) * ODIM + sseg;

    f32x4v acc[4][2];
#pragma unroll
    for (int i = 0; i < 4; ++i)
#pragma unroll
        for (int j = 0; j < 2; ++j) { acc[i][j][0] = 0.f; acc[i][j][1] = 0.f; acc[i][j][2] = 0.f; acc[i][j][3] = 0.f; }

    // ---- prologue: tile 0 -> LDS[0]; issue tile-1 loads ----
    s16x8 ra  = *(const s16x8*)(ga);
    s16x8 rb0 = *(const s16x8*)(gb0);
    s16x8 rb1 = *(const s16x8*)(gb1);
    *(s16x8*)&Ak[0][srow][sseg] = ra;
    *(s16x8*)&Bk[0][srow][sseg] = rb0;
    *(s16x8*)&Bk[0][srow + 64][sseg] = rb1;
    ra  = *(const s16x8*)(ga + 32);
    rb0 = *(const s16x8*)(gb0 + 32);
    rb1 = *(const s16x8*)(gb1 + 32);
    wg_barrier_lds();

    int buf = 0;
    for (int kt = 0; kt < PROJ_KIT; ++kt) {
        s16x8 af[4], bfr[2];
#pragma unroll
        for (int i = 0; i < 4; ++i) af[i] = *(const s16x8*)&Ak[buf][i * 16 + l15][quad * 8];
#pragma unroll
        for (int j = 0; j < 2; ++j) bfr[j] = *(const s16x8*)&Bk[buf][wv * 32 + j * 16 + l15][quad * 8];

        if (kt + 1 < PROJ_KIT) {
            *(s16x8*)&Ak[buf ^ 1][srow][sseg] = ra;
            *(s16x8*)&Bk[buf ^ 1][srow][sseg] = rb0;
            *(s16x8*)&Bk[buf ^ 1][srow + 64][sseg] = rb1;
            if (kt + 2 < PROJ_KIT) {
                int k0n = (kt + 2) * 32;
                ra  = *(const s16x8*)(ga + k0n);
                rb0 = *(const s16x8*)(gb0 + k0n);
                rb1 = *(const s16x8*)(gb1 + k0n);
            }
        }

        __builtin_amdgcn_s_setprio(1);
#pragma unroll
        for (int i = 0; i < 4; ++i)
#pragma unroll
            for (int j = 0; j < 2; ++j)
                acc[i][j] = __builtin_amdgcn_mfma_f32_16x16x32_bf16(af[i], bfr[j], acc[i][j], 0, 0, 0);
        __builtin_amdgcn_s_setprio(0);

        if (kt + 1 < PROJ_KIT) {
            wg_barrier_lds();
            buf ^= 1;
        }
    }

#pragma unroll
    for (int j = 0; j < 2; ++j) {
        int n = n0 + wv * 32 + j * 16 + l15;
        if (n >= DIM) continue;
        float bp = bproj[n];
#pragma unroll
        for (int i = 0; i < 4; ++i) {
            int mbase = m0 + i * 16 + quad * 4;
#pragma unroll
            for (int r = 0; r < 4; ++r)
                out[(size_t)(mbase + r) * DIM + n] = acc[i][j][r] + bp;
        }
    }
}

// ---------------------------------------------------------------------------
// launch
// ---------------------------------------------------------------------------
extern "C" void kernel_launch(void* const* d_in, const int* in_sizes, int n_in,
                              void* d_out, int out_size, void* d_ws, size_t ws_size,
                              hipStream_t stream) {
    const float* x      = (const float*)d_in[0];  // (16,784,384)
    const float* Wqkv   = (const float*)d_in[1];  // (1536,384)
    const float* Wproj  = (const float*)d_in[2];  // (384,1024)
    const float* bproj  = (const float*)d_in[3];  // (384,)
    const float* table  = (const float*)d_in[4];  // (8,625)
    float* out = (float*)d_out;

    const size_t QK_SZ  = (size_t)B_SZ * NH * L_SEQ * 64;   // shorts
    const size_t VT_SZ  = (size_t)B_SZ * NH * VD * L_SEQ;   // shorts
    const size_t BI_SZ  = (size_t)NH * L_SEQ * L_SEQ;       // floats
    const size_t O2_SZ  = (size_t)B_SZ * L_SEQ * ODIM;      // shorts
    const size_t X_SZ   = (size_t)B_SZ * L_SEQ * DIM;       // shorts
    const size_t WQ_SZ  = (size_t)EDIM * DIM;               // shorts
    const size_t WP_SZ  = (size_t)DIM * ODIM;               // shorts

    short* qkb   = (short*)d_ws;
    short* vTb   = qkb + QK_SZ;
    float* bias  = (float*)(vTb + VT_SZ);
    short* o2    = (short*)(bias + BI_SZ);
    short* xb    = o2 + O2_SZ;
    short* wqkvb = xb + X_SZ;
    short* wprojb= wqkvb + WQ_SZ;

    {
        int n0 = (int)(X_SZ / 8);
        int n1 = (int)(WQ_SZ / 8);
        int n2 = (int)(WP_SZ / 8);
        int tot = n0 + n1 + n2;
        cvt_bf16_all<<<(tot + 255) / 256, 256, 0, stream>>>(x, xb, n0, Wqkv, wqkvb, n1, Wproj, wprojb, n2);
    }

    {
        int quads = (L_SEQ * L_SEQ) / 4;               // 153664
        dim3 grid((quads + 255) / 256, NH);            // (601, 8)
        bias_kernel<<<grid, 256, 0, stream>>>(table, bias);
    }

    qkv_gemm_mfma<<<QKV_NWG, 256, 0, stream>>>(xb, wqkvb, qkb, vTb);

    flash_attn_mfma13<<<B_SZ * NH * NQT8, 512, 0, stream>>>(qkb, vTb, bias, o2);

    proj_gemm_mfma<<<588, 256, 0, stream>>>(o2, wprojb, bproj, out);
}

// Round 15
// 244.351 us; speedup vs baseline: 1.0355x; 1.0355x over previous
//
#include <hip/hip_runtime.h>
#include <cstddef>

#define L_SEQ 784
#define DIM 384
#define B_SZ 16
#define NH 8
#define QKD 32
#define VD 128
#define EDIM 1536   // NH*(2*QKD+VD)
#define RESN 25
#define NPTS 625    // RESN*RESN
#define ODIM 1024   // NH*VD
#define NKT 13      // ceil(784/64) k-tiles
#define QKVD 192    // 2*QKD + VD
#define QBLK 128    // q-rows per block (8 waves x 16)
#define NQT8 7      // ceil(784/128) q-tiles
#define TMP_STR 640 // padded row stride (floats) for separable-bias tmp

typedef short s16x8 __attribute__((ext_vector_type(8)));
typedef short s16x4 __attribute__((ext_vector_type(4)));
typedef float f32x4v __attribute__((ext_vector_type(4)));

__device__ __forceinline__ short f2bf(float f) {
    union { float f; unsigned u; } c; c.f = f;
    unsigned u = c.u;
    return (short)((u + 0x7FFFu + ((u >> 16) & 1u)) >> 16);
}

__device__ __forceinline__ s16x8 ld_frag(const short* p) {
    s16x4 lo = *(const s16x4*)p;
    s16x4 hi = *(const s16x4*)(p + 4);
    s16x8 r;
    r[0] = lo[0]; r[1] = lo[1]; r[2] = lo[2]; r[3] = lo[3];
    r[4] = hi[0]; r[5] = hi[1]; r[6] = hi[2]; r[7] = hi[3];
    return r;
}

__device__ __forceinline__ void st_frag(short* p, s16x8 w) {
    s16x4 lo, hi;
    lo[0] = w[0]; lo[1] = w[1]; lo[2] = w[2]; lo[3] = w[3];
    hi[0] = w[4]; hi[1] = w[5]; hi[2] = w[6]; hi[3] = w[7];
    *(s16x4*)p = lo;
    *(s16x4*)(p + 4) = hi;
}

// Raw workgroup barrier that does NOT drain vmcnt (global prefetches stay in
// flight); waits only this wave's LDS ops, then s_barrier.
__device__ __forceinline__ void wg_barrier_lds() {
    asm volatile("s_waitcnt lgkmcnt(0)" ::: "memory");
    __builtin_amdgcn_s_barrier();
    asm volatile("" ::: "memory");
}

// ---------------------------------------------------------------------------
// fp32 -> bf16 bulk convert, all three tensors in ONE launch (8 elts/thread)
// ---------------------------------------------------------------------------
__global__ __launch_bounds__(256) void cvt_bf16_all(const float* __restrict__ s0, short* __restrict__ d0, int n0,
                                                    const float* __restrict__ s1, short* __restrict__ d1, int n1,
                                                    const float* __restrict__ s2, short* __restrict__ d2, int n2) {
    int i = blockIdx.x * 256 + threadIdx.x;
    const float* s;
    short* d;
    int li;
    if (i < n0) { s = s0; d = d0; li = i; }
    else if (i < n0 + n1) { s = s1; d = d1; li = i - n0; }
    else if (i < n0 + n1 + n2) { s = s2; d = d2; li = i - n0 - n1; }
    else return;
    const float4* sp = (const float4*)(s + (size_t)li * 8);
    float4 a = sp[0], c = sp[1];
    s16x8 w;
    w[0] = f2bf(a.x); w[1] = f2bf(a.y); w[2] = f2bf(a.z); w[3] = f2bf(a.w);
    w[4] = f2bf(c.x); w[5] = f2bf(c.y); w[6] = f2bf(c.z); w[7] = f2bf(c.w);
    *(s16x8*)(d + (size_t)li * 8) = w;
}

// ---------------------------------------------------------------------------
// cubic interpolation weight (a = -0.75) + tap helpers
// ---------------------------------------------------------------------------
__device__ __forceinline__ float cubic_w(float x) {
    float ax = fabsf(x);
    const float a = -0.75f;
    float w1 = ((a + 2.0f) * ax - (a + 3.0f)) * ax * ax + 1.0f;
    float w2 = a * (((ax - 5.0f) * ax + 8.0f) * ax - 4.0f);
    return ax <= 1.0f ? w1 : (ax < 2.0f ? w2 : 0.0f);
}

// taps as (y,x) pairs of the clamped flat index (for pass 1)
__device__ __forceinline__ void interp_taps(int o, float* w, int* ty, int* tx) {
    const float scale = 625.0f / 784.0f;
    float src = ((float)o + 0.5f) * scale - 0.5f;
    float f = floorf(src);
    float t = src - f;
    int fi = (int)f;
    w[0] = cubic_w(t + 1.0f);
    w[1] = cubic_w(t);
    w[2] = cubic_w(1.0f - t);
    w[3] = cubic_w(2.0f - t);
#pragma unroll
    for (int j = 0; j < 4; ++j) {
        int idx = fi - 1 + j;
        idx = idx < 0 ? 0 : (idx > NPTS - 1 ? NPTS - 1 : idx);
        ty[j] = idx / RESN;
        tx[j] = idx % RESN;
    }
}

// taps as clamped flat indices (for pass 2)
__device__ __forceinline__ void interp_taps_flat(int o, float* w, int* ti) {
    const float scale = 625.0f / 784.0f;
    float src = ((float)o + 0.5f) * scale - 0.5f;
    float f = floorf(src);
    float t = src - f;
    int fi = (int)f;
    w[0] = cubic_w(t + 1.0f);
    w[1] = cubic_w(t);
    w[2] = cubic_w(1.0f - t);
    w[3] = cubic_w(2.0f - t);
#pragma unroll
    for (int j = 0; j < 4; ++j) {
        int idx = fi - 1 + j;
        idx = idx < 0 ? 0 : (idx > NPTS - 1 ? NPTS - 1 : idx);
        ti[j] = idx;
    }
}

// ---------------------------------------------------------------------------
// Separable bias, pass 1:  tmp[h][p][i] = sum_b wp[b] * T[dist(i, tap_b(p))]
// (4 gathers/element instead of 16; block = one (p,h) row, table in LDS)
// ---------------------------------------------------------------------------
__global__ __launch_bounds__(256) void bias_pass1(const float* __restrict__ table,
                                                  float* __restrict__ tmp) {
    __shared__ float Tl[NPTS];
    const int p = blockIdx.x;
    const int h = blockIdx.y;
    {
        const float* th = table + (size_t)h * NPTS;
        for (int i = threadIdx.x; i < NPTS; i += 256) Tl[i] = th[i];
    }
    __syncthreads();

    float wp[4]; int py[4], px[4];
    interp_taps(p, wp, py, px);

    float* orow = tmp + ((size_t)h * L_SEQ + p) * TMP_STR;
    for (int i = threadIdx.x; i < NPTS; i += 256) {
        int yi = i / RESN;
        int xi = i - yi * RESN;
        float s = 0.0f;
#pragma unroll
        for (int b = 0; b < 4; ++b) {
            int dy = abs(yi - py[b]);
            int dx = abs(xi - px[b]);
            s += wp[b] * Tl[dy * RESN + dx];
        }
        orow[i] = s;
    }
}

// ---------------------------------------------------------------------------
// Separable bias, pass 2:  biasT[h][p][o] = sum_a wo[a] * tmp[h][p][tap_a(o)]
// (tmp row staged in LDS: 4 LDS reads + taps per output)
// ---------------------------------------------------------------------------
__global__ __launch_bounds__(256) void bias_pass2(const float* __restrict__ tmp,
                                                  float* __restrict__ biasT) {
    __shared__ float row[NPTS];
    const int p = blockIdx.x;
    const int h = blockIdx.y;
    {
        const float* irow = tmp + ((size_t)h * L_SEQ + p) * TMP_STR;
        for (int i = threadIdx.x; i < NPTS; i += 256) row[i] = irow[i];
    }
    __syncthreads();

    float* orow = biasT + ((size_t)h * L_SEQ + p) * L_SEQ;
    for (int o = threadIdx.x; o < L_SEQ; o += 256) {
        float wo[4]; int ti[4];
        interp_taps_flat(o, wo, ti);
        float s = wo[0] * row[ti[0]];
        s += wo[1] * row[ti[1]];
        s += wo[2] * row[ti[2]];
        s += wo[3] * row[ti[3]];
        orow[o] = s;
    }
}

// ---------------------------------------------------------------------------
// qkv GEMM (r10-verified EXACT): 128x128 tile, dbuf LDS, ONE non-draining
// barrier per K-step, global loads 2 tiles ahead.
// Outputs:
//   qkb[bh][seq][64] : q feats 0..31 (pre-scaled), k feats 32..63
//   vT [bh][vd][seq] : V transposed (PV staging layout)
// ---------------------------------------------------------------------------
#define QKV_KIT 12   // DIM/32
__global__ __launch_bounds__(256) void qkv_gemm_mfma(const short* __restrict__ Xb,
                                                     const short* __restrict__ Wb,
                                                     short* __restrict__ qkb,
                                                     short* __restrict__ vT) {
    __shared__ short Ak[2][128][48];
    __shared__ short Bk[2][128][48];

    const int tid = threadIdx.x;
    const int wv = tid >> 6;
    const int lane = tid & 63;
    const int quad = lane >> 4;
    const int l15 = lane & 15;
    const int wr = wv >> 1, wc = wv & 1;
    const int m0 = blockIdx.x * 128;
    const int n0 = blockIdx.y * 128;

    const int srow = tid >> 2;
    const int sseg = (tid & 3) * 8;
    const short* xr0 = Xb + (size_t)(m0 + srow) * DIM + sseg;
    const short* xr1 = Xb + (size_t)(m0 + srow + 64) * DIM + sseg;
    const short* wr0 = Wb + (size_t)(n0 + srow) * DIM + sseg;
    const short* wr1 = Wb + (size_t)(n0 + srow + 64) * DIM + sseg;

    f32x4v acc[4][4];
#pragma unroll
    for (int i = 0; i < 4; ++i)
#pragma unroll
        for (int j = 0; j < 4; ++j) { acc[i][j][0] = 0.f; acc[i][j][1] = 0.f; acc[i][j][2] = 0.f; acc[i][j][3] = 0.f; }

    // ---- prologue: tile 0 -> LDS[0]; issue tile-1 loads ----
    s16x8 ra0 = *(const s16x8*)(xr0);
    s16x8 ra1 = *(const s16x8*)(xr1);
    s16x8 rb0 = *(const s16x8*)(wr0);
    s16x8 rb1 = *(const s16x8*)(wr1);
    *(s16x8*)&Ak[0][srow][sseg] = ra0;
    *(s16x8*)&Ak[0][srow + 64][sseg] = ra1;
    *(s16x8*)&Bk[0][srow][sseg] = rb0;
    *(s16x8*)&Bk[0][srow + 64][sseg] = rb1;
    ra0 = *(const s16x8*)(xr0 + 32);
    ra1 = *(const s16x8*)(xr1 + 32);
    rb0 = *(const s16x8*)(wr0 + 32);
    rb1 = *(const s16x8*)(wr1 + 32);
    wg_barrier_lds();

    int buf = 0;
    for (int kt = 0; kt < QKV_KIT; ++kt) {
        s16x8 af[4], bfr[4];
#pragma unroll
        for (int i = 0; i < 4; ++i) af[i] = *(const s16x8*)&Ak[buf][wr * 64 + i * 16 + l15][quad * 8];
#pragma unroll
        for (int j = 0; j < 4; ++j) bfr[j] = *(const s16x8*)&Bk[buf][wc * 64 + j * 16 + l15][quad * 8];

        if (kt + 1 < QKV_KIT) {
            *(s16x8*)&Ak[buf ^ 1][srow][sseg] = ra0;
            *(s16x8*)&Ak[buf ^ 1][srow + 64][sseg] = ra1;
            *(s16x8*)&Bk[buf ^ 1][srow][sseg] = rb0;
            *(s16x8*)&Bk[buf ^ 1][srow + 64][sseg] = rb1;
            if (kt + 2 < QKV_KIT) {
                int k0n = (kt + 2) * 32;
                ra0 = *(const s16x8*)(xr0 + k0n);
                ra1 = *(const s16x8*)(xr1 + k0n);
                rb0 = *(const s16x8*)(wr0 + k0n);
                rb1 = *(const s16x8*)(wr1 + k0n);
            }
        }

        __builtin_amdgcn_s_setprio(1);
#pragma unroll
        for (int i = 0; i < 4; ++i)
#pragma unroll
            for (int j = 0; j < 4; ++j)
                acc[i][j] = __builtin_amdgcn_mfma_f32_16x16x32_bf16(af[i], bfr[j], acc[i][j], 0, 0, 0);
        __builtin_amdgcn_s_setprio(0);

        if (kt + 1 < QKV_KIT) {
            wg_barrier_lds();
            buf ^= 1;
        }
    }

    const float SCALE = 0.17677669529663687f;  // 32^-0.5, folded into q rows

#pragma unroll
    for (int j = 0; j < 4; ++j) {
        int n = n0 + wc * 64 + j * 16 + l15;
        int head = n / QKVD;
        int rr = n - head * QKVD;
        if (rr < 64) {
            float sc = rr < QKD ? SCALE : 1.0f;
#pragma unroll
            for (int i = 0; i < 4; ++i) {
                int mbase = m0 + wr * 64 + i * 16 + quad * 4;
                int bidx = mbase / L_SEQ;       // 4-run never crosses (784 % 4 == 0)
                int l0 = mbase - bidx * L_SEQ;
                size_t base = ((size_t)(bidx * NH + head) * L_SEQ + l0) * 64 + rr;
#pragma unroll
                for (int r = 0; r < 4; ++r)
                    qkb[base + (size_t)r * 64] = f2bf(acc[i][j][r] * sc);
            }
        } else {
            int vd = rr - 64;
#pragma unroll
            for (int i = 0; i < 4; ++i) {
                int mbase = m0 + wr * 64 + i * 16 + quad * 4;
                int bidx = mbase / L_SEQ;
                int l0 = mbase - bidx * L_SEQ;
                s16x4 pk;
#pragma unroll
                for (int r = 0; r < 4; ++r) pk[r] = f2bf(acc[i][j][r]);
                *(s16x4*)&vT[((size_t)(bidx * NH + head) * VD + vd) * L_SEQ + l0] = pk;
            }
        }
    }
}

// ---------------------------------------------------------------------------
// Flash attention v13 (r9-verified, ~99 us): UNCHANGED.
// ---------------------------------------------------------------------------
__global__ __launch_bounds__(512, 4) void flash_attn_mfma13(const short* __restrict__ qkb,
                                                            const short* __restrict__ vT,
                                                            const float* __restrict__ biasT,
                                                            short* __restrict__ o2) {
    __shared__ short Vt[2][VD][68];   // [buf][v-col][k 0..63]  34816 B
    __shared__ short Ps[QBLK][72];    // [q-row][k 0..63] wave-private  18432 B

    const int tid = threadIdx.x;
    const int wv = tid >> 6;          // 0..7
    const int lane = tid & 63;
    const int quad = lane >> 4;
    const int l15 = lane & 15;

    const int h = blockIdx.x & 7;
    const int slot = blockIdx.x >> 3;
    const int b = slot / NQT8;
    const int qt = slot - b * NQT8;
    const int bh = b * NH + h;
    const int q0 = qt * QBLK;

    const short* qkp = qkb + (size_t)bh * L_SEQ * 64;
    const short* vp = vT + (size_t)bh * VD * L_SEQ;

    // V staging addressing: 512 threads cover 128 vd-rows x 4 col-groups of 16
    const int vd = tid >> 2;           // v-dim 0..127
    const int vc0 = (tid & 3) * 16;    // k-col 0/16/32/48
    const short* vline = vp + (size_t)vd * L_SEQ;

    // ---- Q fragment (B operand): lane l15 = q-row, quad*8 = d ----
    int gqq = q0 + wv * 16 + l15;
    if (gqq > L_SEQ - 1) gqq = L_SEQ - 1;   // dup tail row; discarded at store
    const float* brow = biasT + (size_t)h * L_SEQ * L_SEQ + (size_t)gqq * L_SEQ;
    s16x8 qfrag = *(const s16x8*)(qkp + (size_t)gqq * 64 + quad * 8);

    // ---- prologue: V tile 0 -> Vt[0]; issue tile-1 loads ----
    s16x8 va[2];
#pragma unroll
    for (int j = 0; j < 2; ++j) va[j] = *(const s16x8*)(vline + vc0 + j * 8);
#pragma unroll
    for (int j = 0; j < 2; ++j) st_frag(&Vt[0][vd][vc0 + j * 8], va[j]);
    {
#pragma unroll
        for (int j = 0; j < 2; ++j) {
            int cb = 64 + vc0 + j * 8;
            va[j] = *(const s16x8*)(vline + cb);
        }
    }

    // ---- K fragments (A operand) + bias row-slices for tile 0 ----
    s16x8 kf[4];
    f32x4v bcur[4];
#pragma unroll
    for (int t = 0; t < 4; ++t) {
        kf[t] = *(const s16x8*)(qkp + (size_t)(t * 16 + l15) * 64 + 32 + quad * 8);
        float4 bv = *(const float4*)(brow + t * 16 + quad * 4);
        bcur[t][0] = bv.x; bcur[t][1] = bv.y; bcur[t][2] = bv.z; bcur[t][3] = bv.w;
    }

    wg_barrier_lds();   // Vt[0] visible; global prefetches stay in flight

    f32x4v oacc[8];
#pragma unroll
    for (int vt = 0; vt < 8; ++vt) { oacc[vt][0] = 0.f; oacc[vt][1] = 0.f; oacc[vt][2] = 0.f; oacc[vt][3] = 0.f; }
    float lp = 0.f;     // this lane's q-row partial denominator
    int buf = 0;

    for (int kt = 0; kt < NKT; ++kt) {
        const int k0 = kt * 64;

        // ---- QK^T swapped: D[m=k][n=q]; lane holds q=l15, k=t*16+quad*4+r ----
        f32x4v s[4];
        __builtin_amdgcn_s_setprio(1);
#pragma unroll
        for (int t = 0; t < 4; ++t) {
            f32x4v z; z[0] = 0.f; z[1] = 0.f; z[2] = 0.f; z[3] = 0.f;
            s[t] = __builtin_amdgcn_mfma_f32_16x16x32_bf16(kf[t], qfrag, z, 0, 0, 0);
        }
        __builtin_amdgcn_s_setprio(0);
#pragma unroll
        for (int t = 0; t < 4; ++t) s[t] += bcur[t];

        // ---- prefetch K + bias for tile kt+1 (hidden under exp/P/PV) ----
        if (kt + 1 < NKT) {
            int k0n = k0 + 64;
#pragma unroll
            for (int t = 0; t < 4; ++t) {
                int row = k0n + t * 16 + l15;
                if (row > L_SEQ - 1) row = L_SEQ - 1;
                kf[t] = *(const s16x8*)(qkp + (size_t)row * 64 + 32 + quad * 8);
                int c = k0n + t * 16 + quad * 4;
                if (c > L_SEQ - 4) c = L_SEQ - 4;
                float4 bv = *(const float4*)(brow + c);
                bcur[t][0] = bv.x; bcur[t][1] = bv.y; bcur[t][2] = bv.z; bcur[t][3] = bv.w;
            }
        }

        // ---- k-tail mask (uniform per (t,quad): 784 % 4 == 0) ----
        if (kt == NKT - 1) {
#pragma unroll
            for (int t = 0; t < 4; ++t) {
                if (k0 + t * 16 + quad * 4 >= L_SEQ) {
                    s[t][0] = -1e30f; s[t][1] = -1e30f; s[t][2] = -1e30f; s[t][3] = -1e30f;
                }
            }
        }

        // ---- exp + pack + packed P store (4x ds_write_b64, wave-private) ----
#pragma unroll
        for (int t = 0; t < 4; ++t) {
            s16x4 pk;
#pragma unroll
            for (int r = 0; r < 4; ++r) {
                float p = __expf(s[t][r]);
                lp += p;
                pk[r] = f2bf(p);
            }
            *(s16x4*)&Ps[wv * 16 + l15][t * 16 + quad * 4] = pk;
        }

        // ---- stage V tile kt+1 into IDLE buffer (no WAR barrier needed) ----
        if (kt + 1 < NKT) {
#pragma unroll
            for (int j = 0; j < 2; ++j) st_frag(&Vt[buf ^ 1][vd][vc0 + j * 8], va[j]);
            if (kt + 2 < NKT) {
                int k0n2 = (kt + 2) * 64;
#pragma unroll
                for (int j = 0; j < 2; ++j) {
                    int cb = k0n2 + vc0 + j * 8;
                    if (cb > L_SEQ - 8) cb = L_SEQ - 8;
                    va[j] = *(const s16x8*)(vline + cb);
                }
            }
        }

        // ---- P fragments (same-wave LDS ordering; no barrier) ----
        s16x8 pf0 = *(const s16x8*)&Ps[wv * 16 + l15][quad * 8];
        s16x8 pf1 = *(const s16x8*)&Ps[wv * 16 + l15][32 + quad * 8];

        // ---- PV: 16 MFMAs reading Vt[buf] ----
        __builtin_amdgcn_s_setprio(1);
#pragma unroll
        for (int vt = 0; vt < 8; ++vt) {
            int n = vt * 16 + l15;
            s16x8 b0 = ld_frag(&Vt[buf][n][quad * 8]);
            oacc[vt] = __builtin_amdgcn_mfma_f32_16x16x32_bf16(pf0, b0, oacc[vt], 0, 0, 0);
            s16x8 b1 = ld_frag(&Vt[buf][n][32 + quad * 8]);
            oacc[vt] = __builtin_amdgcn_mfma_f32_16x16x32_bf16(pf1, b1, oacc[vt], 0, 0, 0);
        }
        __builtin_amdgcn_s_setprio(0);

        // ---- single barrier per tile: V(kt+1) writes visible to all waves ----
        if (kt + 1 < NKT) {
            wg_barrier_lds();
            buf ^= 1;
        }
    }

    // ---- epilogue (r3/r6-verified): row sum across the 4 quads, store ----
    float lsum = lp;
    lsum += __shfl_xor(lsum, 16);
    lsum += __shfl_xor(lsum, 32);
    float inv[4];
#pragma unroll
    for (int r = 0; r < 4; ++r)
        inv[r] = 1.0f / __shfl(lsum, quad * 4 + r, 16);

#pragma unroll
    for (int r = 0; r < 4; ++r) {
        int gqs = q0 + wv * 16 + quad * 4 + r;
        if (gqs >= L_SEQ) continue;
        short* dst = o2 + ((size_t)b * L_SEQ + gqs) * ODIM + h * VD;
#pragma unroll
        for (int vt = 0; vt < 8; ++vt)
            dst[vt * 16 + l15] = f2bf(oacc[vt][r] * inv[r]);
    }
}

// ---------------------------------------------------------------------------
// proj GEMM (r10-verified EXACT): 128x128 tile, dbuf LDS, one raw
// barrier/iter, loads 2 tiles ahead.  out = o2 @ WprojT + bproj (fp32)
// ---------------------------------------------------------------------------
#define PROJ_KIT 32   // ODIM/32
__global__ __launch_bounds__(256) void proj_gemm_mfma(const short* __restrict__ Xb,
                                                      const short* __restrict__ Wb,
                                                      const float* __restrict__ bproj,
                                                      float* __restrict__ out) {
    __shared__ short Ak[2][128][48];
    __shared__ short Bk[2][128][48];

    const int tid = threadIdx.x;
    const int wv = tid >> 6;
    const int lane = tid & 63;
    const int quad = lane >> 4;
    const int l15 = lane & 15;
    const int wr = wv >> 1, wc = wv & 1;
    const int m0 = blockIdx.x * 128;
    const int n0 = blockIdx.y * 128;

    const int srow = tid >> 2;
    const int sseg = (tid & 3) * 8;
    const short* xr0 = Xb + (size_t)(m0 + srow) * ODIM + sseg;
    const short* xr1 = Xb + (size_t)(m0 + srow + 64) * ODIM + sseg;
    const short* wr0 = Wb + (size_t)(n0 + srow) * ODIM + sseg;
    const short* wr1 = Wb + (size_t)(n0 + srow + 64) * ODIM + sseg;

    f32x4v acc[4][4];
#pragma unroll
    for (int i = 0; i < 4; ++i)
#pragma unroll
        for (int j = 0; j < 4; ++j) { acc[i][j][0] = 0.f; acc[i][j][1] = 0.f; acc[i][j][2] = 0.f; acc[i][j][3] = 0.f; }

    // ---- prologue: tile 0 -> LDS[0]; issue tile-1 loads ----
    s16x8 ra0 = *(const s16x8*)(xr0);
    s16x8 ra1 = *(const s16x8*)(xr1);
    s16x8 rb0 = *(const s16x8*)(wr0);
    s16x8 rb1 = *(const s16x8*)(wr1);
    *(s16x8*)&Ak[0][srow][sseg] = ra0;
    *(s16x8*)&Ak[0][srow + 64][sseg] = ra1;
    *(s16x8*)&Bk[0][srow][sseg] = rb0;
    *(s16x8*)&Bk[0][srow + 64][sseg] = rb1;
    ra0 = *(const s16x8*)(xr0 + 32);
    ra1 = *(const s16x8*)(xr1 + 32);
    rb0 = *(const s16x8*)(wr0 + 32);
    rb1 = *(const s16x8*)(wr1 + 32);
    wg_barrier_lds();

    int buf = 0;
    for (int kt = 0; kt < PROJ_KIT; ++kt) {
        s16x8 af[4], bfr[4];
#pragma unroll
        for (int i = 0; i < 4; ++i) af[i] = *(const s16x8*)&Ak[buf][wr * 64 + i * 16 + l15][quad * 8];
#pragma unroll
        for (int j = 0; j < 4; ++j) bfr[j] = *(const s16x8*)&Bk[buf][wc * 64 + j * 16 + l15][quad * 8];

        if (kt + 1 < PROJ_KIT) {
            *(s16x8*)&Ak[buf ^ 1][srow][sseg] = ra0;
            *(s16x8*)&Ak[buf ^ 1][srow + 64][sseg] = ra1;
            *(s16x8*)&Bk[buf ^ 1][srow][sseg] = rb0;
            *(s16x8*)&Bk[buf ^ 1][srow + 64][sseg] = rb1;
            if (kt + 2 < PROJ_KIT) {
                int k0n = (kt + 2) * 32;
                ra0 = *(const s16x8*)(xr0 + k0n);
                ra1 = *(const s16x8*)(xr1 + k0n);
                rb0 = *(const s16x8*)(wr0 + k0n);
                rb1 = *(const s16x8*)(wr1 + k0n);
            }
        }

        __builtin_amdgcn_s_setprio(1);
#pragma unroll
        for (int i = 0; i < 4; ++i)
#pragma unroll
            for (int j = 0; j < 4; ++j)
                acc[i][j] = __builtin_amdgcn_mfma_f32_16x16x32_bf16(af[i], bfr[j], acc[i][j], 0, 0, 0);
        __builtin_amdgcn_s_setprio(0);

        if (kt + 1 < PROJ_KIT) {
            wg_barrier_lds();
            buf ^= 1;
        }
    }

#pragma unroll
    for (int j = 0; j < 4; ++j) {
        int n = n0 + wc * 64 + j * 16 + l15;
        if (n >= DIM) continue;
        float bp = bproj[n];
#pragma unroll
        for (int i = 0; i < 4; ++i) {
            int mbase = m0 + wr * 64 + i * 16 + quad * 4;
#pragma unroll
            for (int r = 0; r < 4; ++r)
                out[(size_t)(mbase + r) * DIM + n] = acc[i][j][r] + bp;
        }
    }
}

// ---------------------------------------------------------------------------
// launch
// ---------------------------------------------------------------------------
extern "C" void kernel_launch(void* const* d_in, const int* in_sizes, int n_in,
                              void* d_out, int out_size, void* d_ws, size_t ws_size,
                              hipStream_t stream) {
    const float* x      = (const float*)d_in[0];  // (16,784,384)
    const float* Wqkv   = (const float*)d_in[1];  // (1536,384)
    const float* Wproj  = (const float*)d_in[2];  // (384,1024)
    const float* bproj  = (const float*)d_in[3];  // (384,)
    const float* table  = (const float*)d_in[4];  // (8,625)
    float* out = (float*)d_out;

    const size_t QK_SZ  = (size_t)B_SZ * NH * L_SEQ * 64;   // shorts
    const size_t VT_SZ  = (size_t)B_SZ * NH * VD * L_SEQ;   // shorts
    const size_t BI_SZ  = (size_t)NH * L_SEQ * L_SEQ;       // floats
    const size_t O2_SZ  = (size_t)B_SZ * L_SEQ * ODIM;      // shorts
    const size_t X_SZ   = (size_t)B_SZ * L_SEQ * DIM;       // shorts
    const size_t WQ_SZ  = (size_t)EDIM * DIM;               // shorts
    const size_t WP_SZ  = (size_t)DIM * ODIM;               // shorts

    short* qkb   = (short*)d_ws;
    short* vTb   = qkb + QK_SZ;
    float* bias  = (float*)(vTb + VT_SZ);
    short* o2    = (short*)(bias + BI_SZ);
    short* xb    = o2 + O2_SZ;
    short* wqkvb = xb + X_SZ;
    short* wprojb= wqkvb + WQ_SZ;

    // Separable-bias intermediate ALIASES the o2 region (o2 is dead until
    // flash writes it; tmp is dead after bias_pass2).  16.1 MB <= 25.7 MB.
    float* tmp = (float*)o2;

    {
        int n0 = (int)(X_SZ / 8);
        int n1 = (int)(WQ_SZ / 8);
        int n2 = (int)(WP_SZ / 8);
        int tot = n0 + n1 + n2;
        cvt_bf16_all<<<(tot + 255) / 256, 256, 0, stream>>>(x, xb, n0, Wqkv, wqkvb, n1, Wproj, wprojb, n2);
    }

    {
        dim3 grid(L_SEQ, NH);   // (784, 8): one (p,h) row per block
        bias_pass1<<<grid, 256, 0, stream>>>(table, tmp);
        bias_pass2<<<grid, 256, 0, stream>>>(tmp, bias);
    }

    {
        dim3 grid(12544 / 128, EDIM / 128);  // (98, 12)
        qkv_gemm_mfma<<<grid, 256, 0, stream>>>(xb, wqkvb, qkb, vTb);
    }

    flash_attn_mfma13<<<B_SZ * NH * NQT8, 512, 0, stream>>>(qkb, vTb, bias, o2);

    {
        dim3 grid(12544 / 128, 3);           // (98, 3)
        proj_gemm_mfma<<<grid, 256, 0, stream>>>(o2, wprojb, bproj, out);
    }
}

// Round 16
// 238.840 us; speedup vs baseline: 1.0594x; 1.0231x over previous
//
#include <hip/hip_runtime.h>
#include <cstddef>

#define L_SEQ 784
#define DIM 384
#define B_SZ 16
#define NH 8
#define QKD 32
#define VD 128
#define EDIM 1536   // NH*(2*QKD+VD)
#define RESN 25
#define NPTS 625    // RESN*RESN
#define ODIM 1024   // NH*VD
#define NKT 13      // ceil(784/64) k-tiles
#define QKVD 192    // 2*QKD + VD
#define QBLK 128    // q-rows per block (8 waves x 16)
#define NQT8 7      // ceil(784/128) q-tiles

typedef short s16x8 __attribute__((ext_vector_type(8)));
typedef short s16x4 __attribute__((ext_vector_type(4)));
typedef float f32x4v __attribute__((ext_vector_type(4)));

__device__ __forceinline__ short f2bf(float f) {
    union { float f; unsigned u; } c; c.f = f;
    unsigned u = c.u;
    return (short)((u + 0x7FFFu + ((u >> 16) & 1u)) >> 16);
}

__device__ __forceinline__ s16x8 ld_frag(const short* p) {
    s16x4 lo = *(const s16x4*)p;
    s16x4 hi = *(const s16x4*)(p + 4);
    s16x8 r;
    r[0] = lo[0]; r[1] = lo[1]; r[2] = lo[2]; r[3] = lo[3];
    r[4] = hi[0]; r[5] = hi[1]; r[6] = hi[2]; r[7] = hi[3];
    return r;
}

__device__ __forceinline__ void st_frag(short* p, s16x8 w) {
    s16x4 lo, hi;
    lo[0] = w[0]; lo[1] = w[1]; lo[2] = w[2]; lo[3] = w[3];
    hi[0] = w[4]; hi[1] = w[5]; hi[2] = w[6]; hi[3] = w[7];
    *(s16x4*)p = lo;
    *(s16x4*)(p + 4) = hi;
}

// Raw workgroup barrier that does NOT drain vmcnt (global prefetches stay in
// flight); waits only this wave's LDS ops, then s_barrier.
__device__ __forceinline__ void wg_barrier_lds() {
    asm volatile("s_waitcnt lgkmcnt(0)" ::: "memory");
    __builtin_amdgcn_s_barrier();
    asm volatile("" ::: "memory");
}

// ---------------------------------------------------------------------------
// fp32 -> bf16 bulk convert, all three tensors in ONE launch (8 elts/thread)
// ---------------------------------------------------------------------------
__global__ __launch_bounds__(256) void cvt_bf16_all(const float* __restrict__ s0, short* __restrict__ d0, int n0,
                                                    const float* __restrict__ s1, short* __restrict__ d1, int n1,
                                                    const float* __restrict__ s2, short* __restrict__ d2, int n2) {
    int i = blockIdx.x * 256 + threadIdx.x;
    const float* s;
    short* d;
    int li;
    if (i < n0) { s = s0; d = d0; li = i; }
    else if (i < n0 + n1) { s = s1; d = d1; li = i - n0; }
    else if (i < n0 + n1 + n2) { s = s2; d = d2; li = i - n0 - n1; }
    else return;
    const float4* sp = (const float4*)(s + (size_t)li * 8);
    float4 a = sp[0], c = sp[1];
    s16x8 w;
    w[0] = f2bf(a.x); w[1] = f2bf(a.y); w[2] = f2bf(a.z); w[3] = f2bf(a.w);
    w[4] = f2bf(c.x); w[5] = f2bf(c.y); w[6] = f2bf(c.z); w[7] = f2bf(c.w);
    *(s16x8*)(d + (size_t)li * 8) = w;
}

// ---------------------------------------------------------------------------
// cubic interpolation weight (a = -0.75) + tap helpers
// ---------------------------------------------------------------------------
__device__ __forceinline__ float cubic_w(float x) {
    float ax = fabsf(x);
    const float a = -0.75f;
    float w1 = ((a + 2.0f) * ax - (a + 3.0f)) * ax * ax + 1.0f;
    float w2 = a * (((ax - 5.0f) * ax + 8.0f) * ax - 4.0f);
    return ax <= 1.0f ? w1 : (ax < 2.0f ? w2 : 0.0f);
}

// taps as (y,x) pairs of the clamped flat index
__device__ __forceinline__ void interp_taps(int o, float* w, int* ty, int* tx) {
    const float scale = 625.0f / 784.0f;
    float src = ((float)o + 0.5f) * scale - 0.5f;
    float f = floorf(src);
    float t = src - f;
    int fi = (int)f;
    w[0] = cubic_w(t + 1.0f);
    w[1] = cubic_w(t);
    w[2] = cubic_w(1.0f - t);
    w[3] = cubic_w(2.0f - t);
#pragma unroll
    for (int j = 0; j < 4; ++j) {
        int idx = fi - 1 + j;
        idx = idx < 0 ? 0 : (idx > NPTS - 1 ? NPTS - 1 : idx);
        ty[j] = idx / RESN;
        tx[j] = idx % RESN;
    }
}

// taps as clamped flat indices
__device__ __forceinline__ void interp_taps_flat(int o, float* w, int* ti) {
    const float scale = 625.0f / 784.0f;
    float src = ((float)o + 0.5f) * scale - 0.5f;
    float f = floorf(src);
    float t = src - f;
    int fi = (int)f;
    w[0] = cubic_w(t + 1.0f);
    w[1] = cubic_w(t);
    w[2] = cubic_w(1.0f - t);
    w[3] = cubic_w(2.0f - t);
#pragma unroll
    for (int j = 0; j < 4; ++j) {
        int idx = fi - 1 + j;
        idx = idx < 0 ? 0 : (idx > NPTS - 1 ? NPTS - 1 : idx);
        ti[j] = idx;
    }
}

// ---------------------------------------------------------------------------
// Separable bias, FUSED (r16): per (p,h) block —
//   1) stage table row (625 f32) in LDS
//   2) row[i] = sum_b wp[b] * T[dist(i, tap_b(p))]   (into LDS, no global)
//   3) biasT[h][p][o] = sum_a wo[a] * row[tap_a(o)]
// Arithmetic identical to the r15 two-pass version (same ops, same order);
// deletes the 2x16.1 MB tmp global round-trip + one launch.
// ---------------------------------------------------------------------------
__global__ __launch_bounds__(256) void bias_fused(const float* __restrict__ table,
                                                  float* __restrict__ biasT) {
    __shared__ float Tl[NPTS];
    __shared__ float row[NPTS];
    const int p = blockIdx.x;
    const int h = blockIdx.y;
    {
        const float* th = table + (size_t)h * NPTS;
        for (int i = threadIdx.x; i < NPTS; i += 256) Tl[i] = th[i];
    }
    __syncthreads();

    float wp[4]; int py[4], px[4];
    interp_taps(p, wp, py, px);

    for (int i = threadIdx.x; i < NPTS; i += 256) {
        int yi = i / RESN;
        int xi = i - yi * RESN;
        float s = 0.0f;
#pragma unroll
        for (int b = 0; b < 4; ++b) {
            int dy = abs(yi - py[b]);
            int dx = abs(xi - px[b]);
            s += wp[b] * Tl[dy * RESN + dx];
        }
        row[i] = s;
    }
    __syncthreads();

    float* orow = biasT + ((size_t)h * L_SEQ + p) * L_SEQ;
    for (int o = threadIdx.x; o < L_SEQ; o += 256) {
        float wo[4]; int ti[4];
        interp_taps_flat(o, wo, ti);
        float s = wo[0] * row[ti[0]];
        s += wo[1] * row[ti[1]];
        s += wo[2] * row[ti[2]];
        s += wo[3] * row[ti[3]];
        orow[o] = s;
    }
}

// ---------------------------------------------------------------------------
// qkv GEMM (r10-verified EXACT): 128x128 tile, dbuf LDS, ONE non-draining
// barrier per K-step, global loads 2 tiles ahead.
// Outputs:
//   qkb[bh][seq][64] : q feats 0..31 (pre-scaled), k feats 32..63
//   vT [bh][vd][seq] : V transposed (PV staging layout)
// ---------------------------------------------------------------------------
#define QKV_KIT 12   // DIM/32
__global__ __launch_bounds__(256) void qkv_gemm_mfma(const short* __restrict__ Xb,
                                                     const short* __restrict__ Wb,
                                                     short* __restrict__ qkb,
                                                     short* __restrict__ vT) {
    __shared__ short Ak[2][128][48];
    __shared__ short Bk[2][128][48];

    const int tid = threadIdx.x;
    const int wv = tid >> 6;
    const int lane = tid & 63;
    const int quad = lane >> 4;
    const int l15 = lane & 15;
    const int wr = wv >> 1, wc = wv & 1;
    const int m0 = blockIdx.x * 128;
    const int n0 = blockIdx.y * 128;

    const int srow = tid >> 2;
    const int sseg = (tid & 3) * 8;
    const short* xr0 = Xb + (size_t)(m0 + srow) * DIM + sseg;
    const short* xr1 = Xb + (size_t)(m0 + srow + 64) * DIM + sseg;
    const short* wr0 = Wb + (size_t)(n0 + srow) * DIM + sseg;
    const short* wr1 = Wb + (size_t)(n0 + srow + 64) * DIM + sseg;

    f32x4v acc[4][4];
#pragma unroll
    for (int i = 0; i < 4; ++i)
#pragma unroll
        for (int j = 0; j < 4; ++j) { acc[i][j][0] = 0.f; acc[i][j][1] = 0.f; acc[i][j][2] = 0.f; acc[i][j][3] = 0.f; }

    // ---- prologue: tile 0 -> LDS[0]; issue tile-1 loads ----
    s16x8 ra0 = *(const s16x8*)(xr0);
    s16x8 ra1 = *(const s16x8*)(xr1);
    s16x8 rb0 = *(const s16x8*)(wr0);
    s16x8 rb1 = *(const s16x8*)(wr1);
    *(s16x8*)&Ak[0][srow][sseg] = ra0;
    *(s16x8*)&Ak[0][srow + 64][sseg] = ra1;
    *(s16x8*)&Bk[0][srow][sseg] = rb0;
    *(s16x8*)&Bk[0][srow + 64][sseg] = rb1;
    ra0 = *(const s16x8*)(xr0 + 32);
    ra1 = *(const s16x8*)(xr1 + 32);
    rb0 = *(const s16x8*)(wr0 + 32);
    rb1 = *(const s16x8*)(wr1 + 32);
    wg_barrier_lds();

    int buf = 0;
    for (int kt = 0; kt < QKV_KIT; ++kt) {
        s16x8 af[4], bfr[4];
#pragma unroll
        for (int i = 0; i < 4; ++i) af[i] = *(const s16x8*)&Ak[buf][wr * 64 + i * 16 + l15][quad * 8];
#pragma unroll
        for (int j = 0; j < 4; ++j) bfr[j] = *(const s16x8*)&Bk[buf][wc * 64 + j * 16 + l15][quad * 8];

        if (kt + 1 < QKV_KIT) {
            *(s16x8*)&Ak[buf ^ 1][srow][sseg] = ra0;
            *(s16x8*)&Ak[buf ^ 1][srow + 64][sseg] = ra1;
            *(s16x8*)&Bk[buf ^ 1][srow][sseg] = rb0;
            *(s16x8*)&Bk[buf ^ 1][srow + 64][sseg] = rb1;
            if (kt + 2 < QKV_KIT) {
                int k0n = (kt + 2) * 32;
                ra0 = *(const s16x8*)(xr0 + k0n);
                ra1 = *(const s16x8*)(xr1 + k0n);
                rb0 = *(const s16x8*)(wr0 + k0n);
                rb1 = *(const s16x8*)(wr1 + k0n);
            }
        }

        __builtin_amdgcn_s_setprio(1);
#pragma unroll
        for (int i = 0; i < 4; ++i)
#pragma unroll
            for (int j = 0; j < 4; ++j)
                acc[i][j] = __builtin_amdgcn_mfma_f32_16x16x32_bf16(af[i], bfr[j], acc[i][j], 0, 0, 0);
        __builtin_amdgcn_s_setprio(0);

        if (kt + 1 < QKV_KIT) {
            wg_barrier_lds();
            buf ^= 1;
        }
    }

    const float SCALE = 0.17677669529663687f;  // 32^-0.5, folded into q rows

#pragma unroll
    for (int j = 0; j < 4; ++j) {
        int n = n0 + wc * 64 + j * 16 + l15;
        int head = n / QKVD;
        int rr = n - head * QKVD;
        if (rr < 64) {
            float sc = rr < QKD ? SCALE : 1.0f;
#pragma unroll
            for (int i = 0; i < 4; ++i) {
                int mbase = m0 + wr * 64 + i * 16 + quad * 4;
                int bidx = mbase / L_SEQ;       // 4-run never crosses (784 % 4 == 0)
                int l0 = mbase - bidx * L_SEQ;
                size_t base = ((size_t)(bidx * NH + head) * L_SEQ + l0) * 64 + rr;
#pragma unroll
                for (int r = 0; r < 4; ++r)
                    qkb[base + (size_t)r * 64] = f2bf(acc[i][j][r] * sc);
            }
        } else {
            int vd = rr - 64;
#pragma unroll
            for (int i = 0; i < 4; ++i) {
                int mbase = m0 + wr * 64 + i * 16 + quad * 4;
                int bidx = mbase / L_SEQ;
                int l0 = mbase - bidx * L_SEQ;
                s16x4 pk;
#pragma unroll
                for (int r = 0; r < 4; ++r) pk[r] = f2bf(acc[i][j][r]);
                *(s16x4*)&vT[((size_t)(bidx * NH + head) * VD + vd) * L_SEQ + l0] = pk;
            }
        }
    }
}

// ---------------------------------------------------------------------------
// Flash attention v13 (r9-verified, ~99 us): UNCHANGED.
// ---------------------------------------------------------------------------
__global__ __launch_bounds__(512, 4) void flash_attn_mfma13(const short* __restrict__ qkb,
                                                            const short* __restrict__ vT,
                                                            const float* __restrict__ biasT,
                                                            short* __restrict__ o2) {
    __shared__ short Vt[2][VD][68];   // [buf][v-col][k 0..63]  34816 B
    __shared__ short Ps[QBLK][72];    // [q-row][k 0..63] wave-private  18432 B

    const int tid = threadIdx.x;
    const int wv = tid >> 6;          // 0..7
    const int lane = tid & 63;
    const int quad = lane >> 4;
    const int l15 = lane & 15;

    const int h = blockIdx.x & 7;
    const int slot = blockIdx.x >> 3;
    const int b = slot / NQT8;
    const int qt = slot - b * NQT8;
    const int bh = b * NH + h;
    const int q0 = qt * QBLK;

    const short* qkp = qkb + (size_t)bh * L_SEQ * 64;
    const short* vp = vT + (size_t)bh * VD * L_SEQ;

    // V staging addressing: 512 threads cover 128 vd-rows x 4 col-groups of 16
    const int vd = tid >> 2;           // v-dim 0..127
    const int vc0 = (tid & 3) * 16;    // k-col 0/16/32/48
    const short* vline = vp + (size_t)vd * L_SEQ;

    // ---- Q fragment (B operand): lane l15 = q-row, quad*8 = d ----
    int gqq = q0 + wv * 16 + l15;
    if (gqq > L_SEQ - 1) gqq = L_SEQ - 1;   // dup tail row; discarded at store
    const float* brow = biasT + (size_t)h * L_SEQ * L_SEQ + (size_t)gqq * L_SEQ;
    s16x8 qfrag = *(const s16x8*)(qkp + (size_t)gqq * 64 + quad * 8);

    // ---- prologue: V tile 0 -> Vt[0]; issue tile-1 loads ----
    s16x8 va[2];
#pragma unroll
    for (int j = 0; j < 2; ++j) va[j] = *(const s16x8*)(vline + vc0 + j * 8);
#pragma unroll
    for (int j = 0; j < 2; ++j) st_frag(&Vt[0][vd][vc0 + j * 8], va[j]);
    {
#pragma unroll
        for (int j = 0; j < 2; ++j) {
            int cb = 64 + vc0 + j * 8;
            va[j] = *(const s16x8*)(vline + cb);
        }
    }

    // ---- K fragments (A operand) + bias row-slices for tile 0 ----
    s16x8 kf[4];
    f32x4v bcur[4];
#pragma unroll
    for (int t = 0; t < 4; ++t) {
        kf[t] = *(const s16x8*)(qkp + (size_t)(t * 16 + l15) * 64 + 32 + quad * 8);
        float4 bv = *(const float4*)(brow + t * 16 + quad * 4);
        bcur[t][0] = bv.x; bcur[t][1] = bv.y; bcur[t][2] = bv.z; bcur[t][3] = bv.w;
    }

    wg_barrier_lds();   // Vt[0] visible; global prefetches stay in flight

    f32x4v oacc[8];
#pragma unroll
    for (int vt = 0; vt < 8; ++vt) { oacc[vt][0] = 0.f; oacc[vt][1] = 0.f; oacc[vt][2] = 0.f; oacc[vt][3] = 0.f; }
    float lp = 0.f;     // this lane's q-row partial denominator
    int buf = 0;

    for (int kt = 0; kt < NKT; ++kt) {
        const int k0 = kt * 64;

        // ---- QK^T swapped: D[m=k][n=q]; lane holds q=l15, k=t*16+quad*4+r ----
        f32x4v s[4];
        __builtin_amdgcn_s_setprio(1);
#pragma unroll
        for (int t = 0; t < 4; ++t) {
            f32x4v z; z[0] = 0.f; z[1] = 0.f; z[2] = 0.f; z[3] = 0.f;
            s[t] = __builtin_amdgcn_mfma_f32_16x16x32_bf16(kf[t], qfrag, z, 0, 0, 0);
        }
        __builtin_amdgcn_s_setprio(0);
#pragma unroll
        for (int t = 0; t < 4; ++t) s[t] += bcur[t];

        // ---- prefetch K + bias for tile kt+1 (hidden under exp/P/PV) ----
        if (kt + 1 < NKT) {
            int k0n = k0 + 64;
#pragma unroll
            for (int t = 0; t < 4; ++t) {
                int row = k0n + t * 16 + l15;
                if (row > L_SEQ - 1) row = L_SEQ - 1;
                kf[t] = *(const s16x8*)(qkp + (size_t)row * 64 + 32 + quad * 8);
                int c = k0n + t * 16 + quad * 4;
                if (c > L_SEQ - 4) c = L_SEQ - 4;
                float4 bv = *(const float4*)(brow + c);
                bcur[t][0] = bv.x; bcur[t][1] = bv.y; bcur[t][2] = bv.z; bcur[t][3] = bv.w;
            }
        }

        // ---- k-tail mask (uniform per (t,quad): 784 % 4 == 0) ----
        if (kt == NKT - 1) {
#pragma unroll
            for (int t = 0; t < 4; ++t) {
                if (k0 + t * 16 + quad * 4 >= L_SEQ) {
                    s[t][0] = -1e30f; s[t][1] = -1e30f; s[t][2] = -1e30f; s[t][3] = -1e30f;
                }
            }
        }

        // ---- exp + pack + packed P store (4x ds_write_b64, wave-private) ----
#pragma unroll
        for (int t = 0; t < 4; ++t) {
            s16x4 pk;
#pragma unroll
            for (int r = 0; r < 4; ++r) {
                float p = __expf(s[t][r]);
                lp += p;
                pk[r] = f2bf(p);
            }
            *(s16x4*)&Ps[wv * 16 + l15][t * 16 + quad * 4] = pk;
        }

        // ---- stage V tile kt+1 into IDLE buffer (no WAR barrier needed) ----
        if (kt + 1 < NKT) {
#pragma unroll
            for (int j = 0; j < 2; ++j) st_frag(&Vt[buf ^ 1][vd][vc0 + j * 8], va[j]);
            if (kt + 2 < NKT) {
                int k0n2 = (kt + 2) * 64;
#pragma unroll
                for (int j = 0; j < 2; ++j) {
                    int cb = k0n2 + vc0 + j * 8;
                    if (cb > L_SEQ - 8) cb = L_SEQ - 8;
                    va[j] = *(const s16x8*)(vline + cb);
                }
            }
        }

        // ---- P fragments (same-wave LDS ordering; no barrier) ----
        s16x8 pf0 = *(const s16x8*)&Ps[wv * 16 + l15][quad * 8];
        s16x8 pf1 = *(const s16x8*)&Ps[wv * 16 + l15][32 + quad * 8];

        // ---- PV: 16 MFMAs reading Vt[buf] ----
        __builtin_amdgcn_s_setprio(1);
#pragma unroll
        for (int vt = 0; vt < 8; ++vt) {
            int n = vt * 16 + l15;
            s16x8 b0 = ld_frag(&Vt[buf][n][quad * 8]);
            oacc[vt] = __builtin_amdgcn_mfma_f32_16x16x32_bf16(pf0, b0, oacc[vt], 0, 0, 0);
            s16x8 b1 = ld_frag(&Vt[buf][n][32 + quad * 8]);
            oacc[vt] = __builtin_amdgcn_mfma_f32_16x16x32_bf16(pf1, b1, oacc[vt], 0, 0, 0);
        }
        __builtin_amdgcn_s_setprio(0);

        // ---- single barrier per tile: V(kt+1) writes visible to all waves ----
        if (kt + 1 < NKT) {
            wg_barrier_lds();
            buf ^= 1;
        }
    }

    // ---- epilogue (r3/r6-verified): row sum across the 4 quads, store ----
    float lsum = lp;
    lsum += __shfl_xor(lsum, 16);
    lsum += __shfl_xor(lsum, 32);
    float inv[4];
#pragma unroll
    for (int r = 0; r < 4; ++r)
        inv[r] = 1.0f / __shfl(lsum, quad * 4 + r, 16);

#pragma unroll
    for (int r = 0; r < 4; ++r) {
        int gqs = q0 + wv * 16 + quad * 4 + r;
        if (gqs >= L_SEQ) continue;
        short* dst = o2 + ((size_t)b * L_SEQ + gqs) * ODIM + h * VD;
#pragma unroll
        for (int vt = 0; vt < 8; ++vt)
            dst[vt * 16 + l15] = f2bf(oacc[vt][r] * inv[r]);
    }
}

// ---------------------------------------------------------------------------
// proj GEMM (r10-verified EXACT): 128x128 tile, dbuf LDS, one raw
// barrier/iter, loads 2 tiles ahead.  out = o2 @ WprojT + bproj (fp32)
// ---------------------------------------------------------------------------
#define PROJ_KIT 32   // ODIM/32
__global__ __launch_bounds__(256) void proj_gemm_mfma(const short* __restrict__ Xb,
                                                      const short* __restrict__ Wb,
                                                      const float* __restrict__ bproj,
                                                      float* __restrict__ out) {
    __shared__ short Ak[2][128][48];
    __shared__ short Bk[2][128][48];

    const int tid = threadIdx.x;
    const int wv = tid >> 6;
    const int lane = tid & 63;
    const int quad = lane >> 4;
    const int l15 = lane & 15;
    const int wr = wv >> 1, wc = wv & 1;
    const int m0 = blockIdx.x * 128;
    const int n0 = blockIdx.y * 128;

    const int srow = tid >> 2;
    const int sseg = (tid & 3) * 8;
    const short* xr0 = Xb + (size_t)(m0 + srow) * ODIM + sseg;
    const short* xr1 = Xb + (size_t)(m0 + srow + 64) * ODIM + sseg;
    const short* wr0 = Wb + (size_t)(n0 + srow) * ODIM + sseg;
    const short* wr1 = Wb + (size_t)(n0 + srow + 64) * ODIM + sseg;

    f32x4v acc[4][4];
#pragma unroll
    for (int i = 0; i < 4; ++i)
#pragma unroll
        for (int j = 0; j < 4; ++j) { acc[i][j][0] = 0.f; acc[i][j][1] = 0.f; acc[i][j][2] = 0.f; acc[i][j][3] = 0.f; }

    // ---- prologue: tile 0 -> LDS[0]; issue tile-1 loads ----
    s16x8 ra0 = *(const s16x8*)(xr0);
    s16x8 ra1 = *(const s16x8*)(xr1);
    s16x8 rb0 = *(const s16x8*)(wr0);
    s16x8 rb1 = *(const s16x8*)(wr1);
    *(s16x8*)&Ak[0][srow][sseg] = ra0;
    *(s16x8*)&Ak[0][srow + 64][sseg] = ra1;
    *(s16x8*)&Bk[0][srow][sseg] = rb0;
    *(s16x8*)&Bk[0][srow + 64][sseg] = rb1;
    ra0 = *(const s16x8*)(xr0 + 32);
    ra1 = *(const s16x8*)(xr1 + 32);
    rb0 = *(const s16x8*)(wr0 + 32);
    rb1 = *(const s16x8*)(wr1 + 32);
    wg_barrier_lds();

    int buf = 0;
    for (int kt = 0; kt < PROJ_KIT; ++kt) {
        s16x8 af[4], bfr[4];
#pragma unroll
        for (int i = 0; i < 4; ++i) af[i] = *(const s16x8*)&Ak[buf][wr * 64 + i * 16 + l15][quad * 8];
#pragma unroll
        for (int j = 0; j < 4; ++j) bfr[j] = *(const s16x8*)&Bk[buf][wc * 64 + j * 16 + l15][quad * 8];

        if (kt + 1 < PROJ_KIT) {
            *(s16x8*)&Ak[buf ^ 1][srow][sseg] = ra0;
            *(s16x8*)&Ak[buf ^ 1][srow + 64][sseg] = ra1;
            *(s16x8*)&Bk[buf ^ 1][srow][sseg] = rb0;
            *(s16x8*)&Bk[buf ^ 1][srow + 64][sseg] = rb1;
            if (kt + 2 < PROJ_KIT) {
                int k0n = (kt + 2) * 32;
                ra0 = *(const s16x8*)(xr0 + k0n);
                ra1 = *(const s16x8*)(xr1 + k0n);
                rb0 = *(const s16x8*)(wr0 + k0n);
                rb1 = *(const s16x8*)(wr1 + k0n);
            }
        }

        __builtin_amdgcn_s_setprio(1);
#pragma unroll
        for (int i = 0; i < 4; ++i)
#pragma unroll
            for (int j = 0; j < 4; ++j)
                acc[i][j] = __builtin_amdgcn_mfma_f32_16x16x32_bf16(af[i], bfr[j], acc[i][j], 0, 0, 0);
        __builtin_amdgcn_s_setprio(0);

        if (kt + 1 < PROJ_KIT) {
            wg_barrier_lds();
            buf ^= 1;
        }
    }

#pragma unroll
    for (int j = 0; j < 4; ++j) {
        int n = n0 + wc * 64 + j * 16 + l15;
        if (n >= DIM) continue;
        float bp = bproj[n];
#pragma unroll
        for (int i = 0; i < 4; ++i) {
            int mbase = m0 + wr * 64 + i * 16 + quad * 4;
#pragma unroll
            for (int r = 0; r < 4; ++r)
                out[(size_t)(mbase + r) * DIM + n] = acc[i][j][r] + bp;
        }
    }
}

// ---------------------------------------------------------------------------
// launch
// ---------------------------------------------------------------------------
extern "C" void kernel_launch(void* const* d_in, const int* in_sizes, int n_in,
                              void* d_out, int out_size, void* d_ws, size_t ws_size,
                              hipStream_t stream) {
    const float* x      = (const float*)d_in[0];  // (16,784,384)
    const float* Wqkv   = (const float*)d_in[1];  // (1536,384)
    const float* Wproj  = (const float*)d_in[2];  // (384,1024)
    const float* bproj  = (const float*)d_in[3];  // (384,)
    const float* table  = (const float*)d_in[4];  // (8,625)
    float* out = (float*)d_out;

    const size_t QK_SZ  = (size_t)B_SZ * NH * L_SEQ * 64;   // shorts
    const size_t VT_SZ  = (size_t)B_SZ * NH * VD * L_SEQ;   // shorts
    const size_t BI_SZ  = (size_t)NH * L_SEQ * L_SEQ;       // floats
    const size_t O2_SZ  = (size_t)B_SZ * L_SEQ * ODIM;      // shorts
    const size_t X_SZ   = (size_t)B_SZ * L_SEQ * DIM;       // shorts
    const size_t WQ_SZ  = (size_t)EDIM * DIM;               // shorts
    const size_t WP_SZ  = (size_t)DIM * ODIM;               // shorts

    short* qkb   = (short*)d_ws;
    short* vTb   = qkb + QK_SZ;
    float* bias  = (float*)(vTb + VT_SZ);
    short* o2    = (short*)(bias + BI_SZ);
    short* xb    = o2 + O2_SZ;
    short* wqkvb = xb + X_SZ;
    short* wprojb= wqkvb + WQ_SZ;

    {
        int n0 = (int)(X_SZ / 8);
        int n1 = (int)(WQ_SZ / 8);
        int n2 = (int)(WP_SZ / 8);
        int tot = n0 + n1 + n2;
        cvt_bf16_all<<<(tot + 255) / 256, 256, 0, stream>>>(x, xb, n0, Wqkv, wqkvb, n1, Wproj, wprojb, n2);
    }

    {
        dim3 grid(L_SEQ, NH);   // (784, 8): one (p,h) row per block
        bias_fused<<<grid, 256, 0, stream>>>(table, bias);
    }

    {
        dim3 grid(12544 / 128, EDIM / 128);  // (98, 12)
        qkv_gemm_mfma<<<grid, 256, 0, stream>>>(xb, wqkvb, qkb, vTb);
    }

    flash_attn_mfma13<<<B_SZ * NH * NQT8, 512, 0, stream>>>(qkb, vTb, bias, o2);

    {
        dim3 grid(12544 / 128, 3);           // (98, 3)
        proj_gemm_mfma<<<grid, 256, 0, stream>>>(o2, wprojb, bproj, out);
    }
}